// Round 6
// baseline (234.929 us; speedup 1.0000x reference)
//
#include <hip/hip_runtime.h>
#include <math.h>

#define NLAYER_TOT 12
#define LAYER0 4
#define SMAX 512
#define DIM 768
#define NSEG 128  // 4 tokens per segment, 128*4=512 >= T
// B=8, 8 used layers (4..11), T = mask.sum(row0)-1 (511 here)

// packed upper-tri index for 8x8 symmetric gram
__host__ __device__ constexpr int gp(int i, int j) {
    return (i <= j) ? (i * 8 - i * (i - 1) / 2 + (j - i))
                    : (j * 8 - j * (j - 1) / 2 + (i - j));
}

__device__ inline float frcp(float x) { return __builtin_amdgcn_rcpf(x); }
__device__ inline float frsq(float x) { return __builtin_amdgcn_rsqf(x); }

// wave64 reduce-to-all: 4 DPP row_ror adds (VALU rate) + 2 cross-row shuffles (DS)
__device__ inline float wave_reduce_add(float v) {
    v += __int_as_float(__builtin_amdgcn_update_dpp(0, __float_as_int(v), 0x121, 0xF, 0xF, true));
    v += __int_as_float(__builtin_amdgcn_update_dpp(0, __float_as_int(v), 0x122, 0xF, 0xF, true));
    v += __int_as_float(__builtin_amdgcn_update_dpp(0, __float_as_int(v), 0x124, 0xF, 0xF, true));
    v += __int_as_float(__builtin_amdgcn_update_dpp(0, __float_as_int(v), 0x128, 0xF, 0xF, true));
    v += __shfl_xor(v, 16, 64);
    v += __shfl_xor(v, 32, 64);
    return v;
}

// ---------------- per-k small math: Cholesky of Gram subset -> align, nov ----------------
// QR's R equals chol(G) up to per-row sign flips; align & nov are invariant to the flips.
template <int W>
__device__ inline void alpha_nov(const float (&A)[36], const int (&idx)[5],
                                 float& align_o, float& nov_o) {
    float Gs[W][W];
#pragma unroll
    for (int i = 0; i < W; ++i)
#pragma unroll
        for (int j = i; j < W; ++j) {
            float v = A[gp(idx[i], idx[j])];
            Gs[i][j] = v;
            Gs[j][i] = v;
        }
    float R[W][W];
#pragma unroll
    for (int j = 0; j < W; ++j) {
#pragma unroll
        for (int i = 0; i <= j; ++i) {
            float s = Gs[i][j];
#pragma unroll
            for (int q = 0; q < i; ++q) s -= R[q][i] * R[q][j];
            if (i == j) R[i][j] = s * frsq(s);       // sqrt(s)
            else        R[i][j] = s * frcp(R[i][i]); // s / R[i][i]
        }
    }
    float ic[W - 1];
#pragma unroll
    for (int j = 0; j < W - 1; ++j) ic[j] = frsq(Gs[j][j]);  // 1/coln[j]
    float m[W - 1];
#pragma unroll
    for (int i = 0; i < W - 1; ++i) {
        float s = 0.0f;
#pragma unroll
        for (int j = i; j < W - 1; ++j) s += R[i][j] * ic[j];
        m[i] = s * (1.0f / (float)(W - 1));
    }
    float num = 0.0f, n1 = 0.0f;
#pragma unroll
    for (int i = 0; i < W - 1; ++i) {
        num += m[i] * R[i][W - 1];
        n1 += R[i][W - 1] * R[i][W - 1];
    }
    float align_raw = num * frsq(n1);
    align_o = frcp(align_raw * (float)W * 2.0f);
    nov_o = fabsf(R[W - 1][W - 1]) * frsq(Gs[W - 1][W - 1]);
}

// ---------------- single fused kernel, register-resident token slice ----------------
// Round-4 proven publish path: LDS reduce -> device-scope atomicAdd accumulation
// (cross-XCD coherent RMW, no fences) -> zeroed-counter TRUE-last election
// (round-5 lesson: modulo election on poisoned counters elects an EARLY block ->
// reads unpublished slots; counters must be memset each iteration since the
// harness re-poisons the whole workspace).
// Round-6 change: hold the wave's full 24KB token-slice (3 chunks x 8 layers of
// float4) in registers, issued as ONE 24-deep load burst for max MLP; Phases C/D
// L2 re-reads eliminated (48 -> 24 loads/wave, shorter dependency chain).
__global__ __launch_bounds__(256, 2) void k_main(const float* __restrict__ in,
                                                 const int* __restrict__ mask,
                                                 float* __restrict__ Pacc,  // [8][768], pre-zeroed
                                                 float* __restrict__ Vacc,  // [8], pre-zeroed
                                                 int* __restrict__ cnt,     // [8], pre-zeroed
                                                 float* __restrict__ out) { // [8][768]
    int seg = blockIdx.x;  // 0..NSEG-1
    int b = blockIdx.y;    // 0..7
    int tid = threadIdx.x;
    int wave = tid >> 6;
    int lane = tid & 63;

    __shared__ float part[DIM];
    __shared__ float vpart;
    __shared__ float wred[4];
    __shared__ int lastS;

    int t = seg * 4 + wave;  // always < SMAX -> loads in bounds regardless of T
    const float* base = in + ((size_t)(b * NLAYER_TOT + LAYER0) * SMAX + t) * DIM;

    // --- Phase A: issue ALL 24 loads up front (24-deep MLP burst, ~96 VGPR held) ---
    float4 x[3][8];
#pragma unroll
    for (int c = 0; c < 3; ++c)
#pragma unroll
        for (int k = 0; k < 8; ++k)
            x[c][k] = *(const float4*)(base + (size_t)k * SMAX * DIM + c * 256 + lane * 4);

    // LDS init + mask-sum hide under the load latency
    for (int i = tid; i < DIM; i += 256) part[i] = 0.0f;
    if (tid == 0) vpart = 0.0f;
    float mv = (float)(mask[tid] + mask[tid + 256]);  // T from mask row 0, exact in f32
    mv = wave_reduce_add(mv);
    if (lane == 0) wred[wave] = mv;
    __syncthreads();
    int T = (int)(wred[0] + wred[1] + wred[2] + wred[3]) - 1;

    // --- Phase B: gram from registers ---
    float g[36];
#pragma unroll
    for (int p = 0; p < 36; ++p) g[p] = 0.0f;
#pragma unroll
    for (int c = 0; c < 3; ++c) {
        int p = 0;
#pragma unroll
        for (int i = 0; i < 8; ++i)
#pragma unroll
            for (int j = i; j < 8; ++j) {
                g[p] += x[c][i].x * x[c][j].x + x[c][i].y * x[c][j].y +
                        x[c][i].z * x[c][j].z + x[c][i].w * x[c][j].w;
                ++p;
            }
    }
    // wave reduce-to-all
#pragma unroll
    for (int p = 0; p < 36; ++p) g[p] = wave_reduce_add(g[p]);

    // --- Phase C: lane-redundant chol / weights (no memory traffic) ---
    // Reference window tables: left only when k >= WS(=2); right = k+1..min(k+2,7); k last.
    static constexpr int IDX0[5] = {1, 2, 0, 0, 0};
    static constexpr int IDX1[5] = {2, 3, 1, 0, 0};
    static constexpr int IDX2[5] = {0, 1, 3, 4, 2};
    static constexpr int IDX3[5] = {1, 2, 4, 5, 3};
    static constexpr int IDX4[5] = {2, 3, 5, 6, 4};
    static constexpr int IDX5[5] = {3, 4, 6, 7, 5};
    static constexpr int IDX6[5] = {4, 5, 7, 6, 0};
    static constexpr int IDX7[5] = {5, 6, 7, 0, 0};
    float a[8], n[8];
    alpha_nov<3>(g, IDX0, a[0], n[0]);
    alpha_nov<3>(g, IDX1, a[1], n[1]);
    alpha_nov<5>(g, IDX2, a[2], n[2]);
    alpha_nov<5>(g, IDX3, a[3], n[3]);
    alpha_nov<5>(g, IDX4, a[4], n[4]);
    alpha_nov<5>(g, IDX5, a[5], n[5]);
    alpha_nov<4>(g, IDX6, a[6], n[6]);
    alpha_nov<3>(g, IDX7, a[7], n[7]);
    float sa = 0.0f, sn = 0.0f;
#pragma unroll
    for (int k = 0; k < 8; ++k) { sa += a[k]; sn += n[k]; }
    float isa = frcp(sa), isn = frcp(sn);
    float al[8], ss = 0.0f;
#pragma unroll
    for (int k = 0; k < 8; ++k) { al[k] = a[k] * isa + n[k] * isn; ss += al[k]; }
    float iss = frcp(ss);
    // token variance (consecutive-layer cosine sims)
    float c7[7], mu = 0.0f;
#pragma unroll
    for (int i = 0; i < 7; ++i) {
        float denom = g[gp(i, i)] * g[gp(i + 1, i + 1)];
        c7[i] = g[gp(i, i + 1)] * frsq(denom > 1e-16f ? denom : 1e-16f);
        mu += c7[i];
    }
    mu *= (1.0f / 7.0f);
    float var = 0.0f;
#pragma unroll
    for (int i = 0; i < 7; ++i) var += (c7[i] - mu) * (c7[i] - mu);
    float vraw = var * (1.0f / 6.0f);  // ddof=1
    float p8[8];
#pragma unroll
    for (int k = 0; k < 8; ++k) p8[k] = al[k] * iss * vraw;

    // --- Phase D: weighted accumulate straight from registers ---
    float4 acc12[3];
#pragma unroll
    for (int it = 0; it < 3; ++it) acc12[it] = make_float4(0.f, 0.f, 0.f, 0.f);
#pragma unroll
    for (int it = 0; it < 3; ++it)
#pragma unroll
        for (int k = 0; k < 8; ++k) {
            acc12[it].x += p8[k] * x[it][k].x;
            acc12[it].y += p8[k] * x[it][k].y;
            acc12[it].z += p8[k] * x[it][k].z;
            acc12[it].w += p8[k] * x[it][k].w;
        }

    // --- Phase E: block-level reduce into LDS (only tokens < T contribute) ---
    if (t < T) {
#pragma unroll
        for (int it = 0; it < 3; ++it) {
            int d = it * 256 + lane * 4;
            atomicAdd(&part[d + 0], acc12[it].x);
            atomicAdd(&part[d + 1], acc12[it].y);
            atomicAdd(&part[d + 2], acc12[it].z);
            atomicAdd(&part[d + 3], acc12[it].w);
        }
        if (lane == 0) atomicAdd(&vpart, vraw);
    }
    __syncthreads();

    // --- Phase F: publish via device-scope atomic accumulation (no fences) ---
    float* pb = Pacc + (size_t)b * DIM;
    for (int i = tid; i < DIM; i += 256) atomicAdd(&pb[i], part[i]);
    if (tid == 0) atomicAdd(&Vacc[b], vpart);
    __syncthreads();  // drains vmcnt(0): all this block's atomics complete at coherent point

    if (tid == 0) {
        int prev = __hip_atomic_fetch_add(&cnt[b], 1, __ATOMIC_RELAXED,
                                          __HIP_MEMORY_SCOPE_AGENT);
        lastS = (prev == NSEG - 1) ? 1 : 0;  // true-last: cnt zeroed each iteration
    }
    __syncthreads();

    // --- Phase G: last-arriving block for this b finalizes (768 loads + div) ---
    if (lastS) {
        float vs = __hip_atomic_load(&Vacc[b], __ATOMIC_RELAXED, __HIP_MEMORY_SCOPE_AGENT);
        float vinv = 1.0f / vs;
        for (int d = tid; d < DIM; d += 256) {
            float s = __hip_atomic_load(&pb[d], __ATOMIC_RELAXED, __HIP_MEMORY_SCOPE_AGENT);
            out[b * DIM + d] = s * vinv;
        }
    }
}

extern "C" void kernel_launch(void* const* d_in, const int* in_sizes, int n_in,
                              void* d_out, int out_size, void* d_ws, size_t ws_size,
                              hipStream_t stream) {
    const float* hs = (const float*)d_in[0];   // (8, 12, 512, 768) f32
    const int* mask = (const int*)d_in[1];     // (8, 512) i32
    float* out = (float*)d_out;                // (8, 768) f32
    char* ws = (char*)d_ws;
    // ws layout: [0] int cnt[8] | [64] Vacc[8] f | [256] Pacc 8*768 f
    int* cnt = (int*)ws;
    float* Vacc = (float*)(ws + 64);
    float* Pacc = (float*)(ws + 256);

    // zero counters + accumulators (24.8 KB) — required every replay: the harness
    // re-poisons the whole workspace between iterations (round-5 lesson)
    hipMemsetAsync(ws, 0, 256 + (size_t)8 * DIM * sizeof(float), stream);
    k_main<<<dim3(NSEG, 8), 256, 0, stream>>>(hs, mask, Pacc, Vacc, cnt, out);
}

// Round 7
// 216.724 us; speedup vs baseline: 1.0840x; 1.0840x over previous
//
#include <hip/hip_runtime.h>
#include <math.h>

#define NLAYER_TOT 12
#define LAYER0 4
#define SMAX 512
#define DIM 768
#define NSEG 128  // 4 tokens per segment, 128*4=512 >= T
// B=8, 8 used layers (4..11), T = mask.sum(row0)-1 (511 here)

// packed upper-tri index for 8x8 symmetric gram
__host__ __device__ constexpr int gp(int i, int j) {
    return (i <= j) ? (i * 8 - i * (i - 1) / 2 + (j - i))
                    : (j * 8 - j * (j - 1) / 2 + (i - j));
}

__device__ inline float frcp(float x) { return __builtin_amdgcn_rcpf(x); }
__device__ inline float frsq(float x) { return __builtin_amdgcn_rsqf(x); }

// wave64 reduce-to-all: 4 DPP row_ror adds (VALU rate) + 2 cross-row shuffles (DS)
__device__ inline float wave_reduce_add(float v) {
    v += __int_as_float(__builtin_amdgcn_update_dpp(0, __float_as_int(v), 0x121, 0xF, 0xF, true));
    v += __int_as_float(__builtin_amdgcn_update_dpp(0, __float_as_int(v), 0x122, 0xF, 0xF, true));
    v += __int_as_float(__builtin_amdgcn_update_dpp(0, __float_as_int(v), 0x124, 0xF, 0xF, true));
    v += __int_as_float(__builtin_amdgcn_update_dpp(0, __float_as_int(v), 0x128, 0xF, 0xF, true));
    v += __shfl_xor(v, 16, 64);
    v += __shfl_xor(v, 32, 64);
    return v;
}

// ---------------- per-k small math: Cholesky of Gram subset -> align, nov ----------------
// QR's R equals chol(G) up to per-row sign flips; align & nov are invariant to the flips.
template <int W>
__device__ inline void alpha_nov(const float (&A)[36], const int (&idx)[5],
                                 float& align_o, float& nov_o) {
    float Gs[W][W];
#pragma unroll
    for (int i = 0; i < W; ++i)
#pragma unroll
        for (int j = i; j < W; ++j) {
            float v = A[gp(idx[i], idx[j])];
            Gs[i][j] = v;
            Gs[j][i] = v;
        }
    float R[W][W];
#pragma unroll
    for (int j = 0; j < W; ++j) {
#pragma unroll
        for (int i = 0; i <= j; ++i) {
            float s = Gs[i][j];
#pragma unroll
            for (int q = 0; q < i; ++q) s -= R[q][i] * R[q][j];
            if (i == j) R[i][j] = s * frsq(s);       // sqrt(s)
            else        R[i][j] = s * frcp(R[i][i]); // s / R[i][i]
        }
    }
    float ic[W - 1];
#pragma unroll
    for (int j = 0; j < W - 1; ++j) ic[j] = frsq(Gs[j][j]);  // 1/coln[j]
    float m[W - 1];
#pragma unroll
    for (int i = 0; i < W - 1; ++i) {
        float s = 0.0f;
#pragma unroll
        for (int j = i; j < W - 1; ++j) s += R[i][j] * ic[j];
        m[i] = s * (1.0f / (float)(W - 1));
    }
    float num = 0.0f, n1 = 0.0f;
#pragma unroll
    for (int i = 0; i < W - 1; ++i) {
        num += m[i] * R[i][W - 1];
        n1 += R[i][W - 1] * R[i][W - 1];
    }
    float align_raw = num * frsq(n1);
    align_o = frcp(align_raw * (float)W * 2.0f);
    nov_o = fabsf(R[W - 1][W - 1]) * frsq(Gs[W - 1][W - 1]);
}

// ---------------- single fused kernel, NO device fences ----------------
// Round-2 lesson: per-block __threadfence() on gfx950 = L2 writeback per wave ->
// 225 us of cache maintenance. Device-scope atomicAdd accumulation instead
// (cross-XCD coherent by HW, executes at the device-coherent point). __syncthreads()
// drains vmcnt(0) before s_barrier, so the relaxed election counter bump strictly
// follows every thread's completed atomics. Elected last block per b reads the
// accumulators with agent-scope loads.
// Round-5 lesson: cnt must be zeroed each replay (harness re-poisons the whole
// workspace; modulo election on garbage elects an EARLY block -> reads junk).
// Round-6 lesson: keep VGPR <= 128 (this kernel: 88) — 4 waves/SIMD matches the
// grid's 4 blocks/CU; register-resident x[3][8] pushed past 128 and halved
// occupancy (217 -> 235 us). Streaming cur/nxt double-buffer is the optimum.
__global__ __launch_bounds__(256, 2) void k_main(const float* __restrict__ in,
                                                 const int* __restrict__ mask,
                                                 float* __restrict__ Pacc,  // [8][768], pre-zeroed
                                                 float* __restrict__ Vacc,  // [8], pre-zeroed
                                                 int* __restrict__ cnt,     // [8], pre-zeroed
                                                 float* __restrict__ out) { // [8][768]
    int seg = blockIdx.x;  // 0..NSEG-1
    int b = blockIdx.y;    // 0..7
    int tid = threadIdx.x;
    int wave = tid >> 6;
    int lane = tid & 63;

    __shared__ float part[DIM];
    __shared__ float vpart;
    __shared__ float wred[4];
    __shared__ int lastS;

    int t = seg * 4 + wave;  // always < SMAX -> loads in bounds regardless of T
    const float* base = in + ((size_t)(b * NLAYER_TOT + LAYER0) * SMAX + t) * DIM;

    // --- Phase A loads issue FIRST so mask-sum + LDS init hide under HBM latency ---
    float4 cur[8], nxt[8];
#pragma unroll
    for (int k = 0; k < 8; ++k)
        cur[k] = *(const float4*)(base + (size_t)k * SMAX * DIM + lane * 4);

    for (int i = tid; i < DIM; i += 256) part[i] = 0.0f;
    if (tid == 0) vpart = 0.0f;
    // T from mask row 0 (sum of 512 ints, exact in f32)
    float mv = (float)(mask[tid] + mask[tid + 256]);
    mv = wave_reduce_add(mv);
    if (lane == 0) wred[wave] = mv;
    __syncthreads();
    int T = (int)(wred[0] + wred[1] + wred[2] + wred[3]) - 1;

    float4 acc12[3];
#pragma unroll
    for (int it = 0; it < 3; ++it) acc12[it] = make_float4(0.f, 0.f, 0.f, 0.f);

    // --- Phase A: gram with prefetch; x not held past use ---
    float g[36];
#pragma unroll
    for (int p = 0; p < 36; ++p) g[p] = 0.0f;
#pragma unroll
    for (int it = 0; it < 3; ++it) {
        if (it < 2) {
            int d = (it + 1) * 256 + lane * 4;
#pragma unroll
            for (int k = 0; k < 8; ++k)
                nxt[k] = *(const float4*)(base + (size_t)k * SMAX * DIM + d);
        }
        int p = 0;
#pragma unroll
        for (int i = 0; i < 8; ++i)
#pragma unroll
            for (int j = i; j < 8; ++j) {
                g[p] += cur[i].x * cur[j].x + cur[i].y * cur[j].y +
                        cur[i].z * cur[j].z + cur[i].w * cur[j].w;
                ++p;
            }
        if (it < 2) {
#pragma unroll
            for (int k = 0; k < 8; ++k) cur[k] = nxt[k];
        }
    }
    // --- Phase B: wave reduce-to-all ---
#pragma unroll
    for (int p = 0; p < 36; ++p) g[p] = wave_reduce_add(g[p]);

    // --- Phase C: start reload of chunk 0 (L2-hot), then chol under the latency ---
#pragma unroll
    for (int k = 0; k < 8; ++k)
        cur[k] = *(const float4*)(base + (size_t)k * SMAX * DIM + lane * 4);

    // Reference window tables: left only when k >= WS(=2); right = k+1..min(k+2,7); k last.
    static constexpr int IDX0[5] = {1, 2, 0, 0, 0};
    static constexpr int IDX1[5] = {2, 3, 1, 0, 0};
    static constexpr int IDX2[5] = {0, 1, 3, 4, 2};
    static constexpr int IDX3[5] = {1, 2, 4, 5, 3};
    static constexpr int IDX4[5] = {2, 3, 5, 6, 4};
    static constexpr int IDX5[5] = {3, 4, 6, 7, 5};
    static constexpr int IDX6[5] = {4, 5, 7, 6, 0};
    static constexpr int IDX7[5] = {5, 6, 7, 0, 0};
    float a[8], n[8];
    alpha_nov<3>(g, IDX0, a[0], n[0]);
    alpha_nov<3>(g, IDX1, a[1], n[1]);
    alpha_nov<5>(g, IDX2, a[2], n[2]);
    alpha_nov<5>(g, IDX3, a[3], n[3]);
    alpha_nov<5>(g, IDX4, a[4], n[4]);
    alpha_nov<5>(g, IDX5, a[5], n[5]);
    alpha_nov<4>(g, IDX6, a[6], n[6]);
    alpha_nov<3>(g, IDX7, a[7], n[7]);
    float sa = 0.0f, sn = 0.0f;
#pragma unroll
    for (int k = 0; k < 8; ++k) { sa += a[k]; sn += n[k]; }
    float isa = frcp(sa), isn = frcp(sn);
    float al[8], ss = 0.0f;
#pragma unroll
    for (int k = 0; k < 8; ++k) { al[k] = a[k] * isa + n[k] * isn; ss += al[k]; }
    float iss = frcp(ss);
    // token variance (consecutive-layer cosine sims)
    float c[7], mu = 0.0f;
#pragma unroll
    for (int i = 0; i < 7; ++i) {
        float denom = g[gp(i, i)] * g[gp(i + 1, i + 1)];
        c[i] = g[gp(i, i + 1)] * frsq(denom > 1e-16f ? denom : 1e-16f);
        mu += c[i];
    }
    mu *= (1.0f / 7.0f);
    float var = 0.0f;
#pragma unroll
    for (int i = 0; i < 7; ++i) var += (c[i] - mu) * (c[i] - mu);
    float vraw = var * (1.0f / 6.0f);  // ddof=1
    float p8[8];
#pragma unroll
    for (int k = 0; k < 8; ++k) p8[k] = al[k] * iss * vraw;

    // --- Phase D: weighted accumulate, chunks pipelined, reads hit L2 ---
#pragma unroll
    for (int it = 0; it < 3; ++it) {
        if (it < 2) {
            int d = (it + 1) * 256 + lane * 4;
#pragma unroll
            for (int k = 0; k < 8; ++k)
                nxt[k] = *(const float4*)(base + (size_t)k * SMAX * DIM + d);
        }
#pragma unroll
        for (int k = 0; k < 8; ++k) {
            acc12[it].x += p8[k] * cur[k].x;
            acc12[it].y += p8[k] * cur[k].y;
            acc12[it].z += p8[k] * cur[k].z;
            acc12[it].w += p8[k] * cur[k].w;
        }
        if (it < 2) {
#pragma unroll
            for (int k = 0; k < 8; ++k) cur[k] = nxt[k];
        }
    }

    // --- Phase E: block-level reduce into LDS (only tokens < T contribute) ---
    if (t < T) {
#pragma unroll
        for (int it = 0; it < 3; ++it) {
            int d = it * 256 + lane * 4;
            atomicAdd(&part[d + 0], acc12[it].x);
            atomicAdd(&part[d + 1], acc12[it].y);
            atomicAdd(&part[d + 2], acc12[it].z);
            atomicAdd(&part[d + 3], acc12[it].w);
        }
        if (lane == 0) atomicAdd(&vpart, vraw);
    }
    __syncthreads();

    // --- Phase F: publish via device-scope atomic accumulation (no fences) ---
    float* pb = Pacc + (size_t)b * DIM;
    for (int i = tid; i < DIM; i += 256) atomicAdd(&pb[i], part[i]);
    if (tid == 0) atomicAdd(&Vacc[b], vpart);
    __syncthreads();  // drains vmcnt(0): all this block's atomics complete at coherent point

    if (tid == 0) {
        int prev = __hip_atomic_fetch_add(&cnt[b], 1, __ATOMIC_RELAXED,
                                          __HIP_MEMORY_SCOPE_AGENT);
        lastS = (prev == NSEG - 1) ? 1 : 0;  // true-last: cnt zeroed each replay
    }
    __syncthreads();

    // --- Phase G: last-arriving block for this b finalizes (768 loads + div) ---
    if (lastS) {
        float vs = __hip_atomic_load(&Vacc[b], __ATOMIC_RELAXED, __HIP_MEMORY_SCOPE_AGENT);
        float vinv = 1.0f / vs;
        for (int d = tid; d < DIM; d += 256) {
            float s = __hip_atomic_load(&pb[d], __ATOMIC_RELAXED, __HIP_MEMORY_SCOPE_AGENT);
            out[b * DIM + d] = s * vinv;
        }
    }
}

extern "C" void kernel_launch(void* const* d_in, const int* in_sizes, int n_in,
                              void* d_out, int out_size, void* d_ws, size_t ws_size,
                              hipStream_t stream) {
    const float* hs = (const float*)d_in[0];   // (8, 12, 512, 768) f32
    const int* mask = (const int*)d_in[1];     // (8, 512) i32
    float* out = (float*)d_out;                // (8, 768) f32
    char* ws = (char*)d_ws;
    // ws layout: [0] int cnt[8] | [64] Vacc[8] f | [256] Pacc 8*768 f
    int* cnt = (int*)ws;
    float* Vacc = (float*)(ws + 64);
    float* Pacc = (float*)(ws + 256);

    // zero counters + accumulators (24.8 KB) — required every replay: the harness
    // re-poisons the whole workspace between iterations (round-5 lesson)
    hipMemsetAsync(ws, 0, 256 + (size_t)8 * DIM * sizeof(float), stream);
    k_main<<<dim3(NSEG, 8), 256, 0, stream>>>(hs, mask, Pacc, Vacc, cnt, out);
}